// Round 1
// baseline (760.559 us; speedup 1.0000x reference)
//
#include <hip/hip_runtime.h>
#include <cstdint>

typedef long long ll;
typedef unsigned long long ull;

constexpr int N_ = 1024;          // atoms (fixed by problem)
constexpr int BLK = 256;
constexpr int RNDS = 64;
constexpr int CHUNK = BLK * RNDS; // 16384 pairs per block

__device__ __forceinline__ ll rowstart(int i) {
  return (ll)i * (2 * N_ - 1 - i) / 2;
}

// invert triu(N,k=1) linear index -> (i,j)
__device__ __forceinline__ void decode_center(ll p, int& i, int& j) {
  double disc = (double)(2 * N_ - 1) * (double)(2 * N_ - 1) - 8.0 * (double)p;
  int ii = (int)(((double)(2 * N_ - 1) - sqrt(disc)) * 0.5);
  if (ii < 0) ii = 0;
  if (ii > N_ - 2) ii = N_ - 2;
  while (rowstart(ii) > p) --ii;
  while (rowstart(ii + 1) <= p) ++ii;
  i = ii;
  j = ii + 1 + (int)(p - rowstart(ii));
}

// ---------------- kernel 1: classify pairs -> bitmask, block counts, per-atom group counts
__global__ __launch_bounds__(BLK) void k_classify(
    const float* __restrict__ pos, const float* __restrict__ box,
    const int* __restrict__ shifts, int S, ll Pc, ll P,
    ull* __restrict__ mask64, unsigned* __restrict__ blockCount,
    unsigned* __restrict__ cntA, unsigned* __restrict__ cntB,
    unsigned* __restrict__ cntC, unsigned* __restrict__ cntD)
{
  __shared__ float4 sp[N_];
  __shared__ float ssv[16][3];
  __shared__ unsigned wcnt[4];
  int tid = threadIdx.x;
  for (int a = tid; a < N_; a += BLK)
    sp[a] = make_float4(pos[3 * a + 0], pos[3 * a + 1], pos[3 * a + 2], 0.f);
  if (tid < S) {
    for (int k = 0; k < 3; ++k) {
      float acc = 0.f;
      for (int m = 0; m < 3; ++m)
        acc = __fadd_rn(acc, __fmul_rn((float)shifts[3 * tid + m], box[3 * m + k]));
      ssv[tid][k] = acc;
    }
  }
  __syncthreads();
  int lane = tid & 63, wave = tid >> 6;
  ll chunk = (ll)blockIdx.x * CHUNK;
  unsigned wrun = 0;
  for (int r = 0; r < RNDS; ++r) {
    ll p0 = chunk + r * BLK + wave * 64;
    bool inr = (p0 < P);
    bool valid = false;
    if (inr) {
      ll p = p0 + lane;
      int i, j;
      float svx = 0.f, svy = 0.f, svz = 0.f;
      if (p < Pc) {
        decode_center(p, i, j);
      } else {
        ll q = p - Pc;
        int s = (int)(q >> 20);
        i = (int)((q >> 10) & (N_ - 1));
        j = (int)(q & (N_ - 1));
        svx = ssv[s][0]; svy = ssv[s][1]; svz = ssv[s][2];
      }
      float4 pi = sp[i], pj = sp[j];
      // strict IEEE order to match reference: (pi-pj)+sv, (x^2+y^2)+z^2, sqrt, <5
      float dx = __fadd_rn(__fsub_rn(pi.x, pj.x), svx);
      float dy = __fadd_rn(__fsub_rn(pi.y, pj.y), svy);
      float dz = __fadd_rn(__fsub_rn(pi.z, pj.z), svz);
      float d2 = __fadd_rn(__fadd_rn(__fmul_rn(dx, dx), __fmul_rn(dy, dy)),
                           __fmul_rn(dz, dz));
      valid = (sqrtf(d2) < 5.0f);
      if (valid) {
        if (p < Pc) { atomicAdd(&cntA[i], 1u); atomicAdd(&cntC[j], 1u); }
        else        { atomicAdd(&cntB[i], 1u); atomicAdd(&cntD[j], 1u); }
      }
    }
    ull bal = __ballot(valid);
    if (lane == 0) {
      if (inr) mask64[p0 >> 6] = bal;
      wrun += (unsigned)__popcll(bal);
    }
  }
  if (lane == 0) wcnt[wave] = wrun;
  __syncthreads();
  if (tid == 0)
    blockCount[blockIdx.x] = wcnt[0] + wcnt[1] + wcnt[2] + wcnt[3];
}

// ---------------- kernel 2: single-block scans -> blockOff, Vp/V, per-atom group bases
__global__ __launch_bounds__(1024) void k_scan(
    const unsigned* __restrict__ blockCount, unsigned* __restrict__ blockOff, int nb,
    const unsigned* __restrict__ cntA, const unsigned* __restrict__ cntB,
    const unsigned* __restrict__ cntC, const unsigned* __restrict__ cntD,
    unsigned* __restrict__ baseA, unsigned* __restrict__ baseB,
    unsigned* __restrict__ baseC, unsigned* __restrict__ baseD,
    unsigned* __restrict__ scal)
{
  __shared__ unsigned sm[1024];
  int t = threadIdx.x;
  unsigned v = (t < nb) ? blockCount[t] : 0u;
  sm[t] = v;
  for (int off = 1; off < 1024; off <<= 1) {
    __syncthreads();
    unsigned x = (t >= off) ? sm[t - off] : 0u;
    __syncthreads();
    sm[t] += x;
  }
  __syncthreads();
  if (t < nb) blockOff[t] = sm[t] - v;
  unsigned Vp = sm[1023];
  if (t == 0) { scal[0] = Vp; scal[1] = 2u * Vp; }
  __syncthreads();
  unsigned a4 = cntA[t], b4 = cntB[t], c4 = cntC[t], d4 = cntD[t];
  unsigned tot = a4 + b4 + c4 + d4;
  sm[t] = tot;
  for (int off = 1; off < 1024; off <<= 1) {
    __syncthreads();
    unsigned x = (t >= off) ? sm[t - off] : 0u;
    __syncthreads();
    sm[t] += x;
  }
  __syncthreads();
  unsigned excl = sm[t] - tot;
  baseA[t] = excl;
  baseB[t] = excl + a4;
  baseC[t] = excl + a4 + b4;
  baseD[t] = excl + a4 + b4 + c4;
}

// ---------------- kernel 3: scatter valid records (wave per (atom,group), stable ballot ranks)
__global__ __launch_bounds__(BLK) void k_valid(
    const ull* __restrict__ mask64, const float* __restrict__ box,
    const int* __restrict__ shifts, int S, ll Pc, ll T,
    const unsigned* __restrict__ baseA, const unsigned* __restrict__ baseB,
    const unsigned* __restrict__ baseC, const unsigned* __restrict__ baseD,
    float* __restrict__ out)
{
  __shared__ float ssv[16][3];
  int a = blockIdx.x;
  int tid = threadIdx.x, lane = tid & 63, wave = tid >> 6;
  if (tid < S) {
    for (int k = 0; k < 3; ++k) {
      float acc = 0.f;
      for (int m = 0; m < 3; ++m)
        acc = __fadd_rn(acc, __fmul_rn((float)shifts[3 * tid + m], box[3 * m + k]));
      ssv[tid][k] = acc;
    }
  }
  __syncthreads();
  float* oi = out;
  float* oj = out + T;
  float* oo = out + 2 * T;
  float* ov = out + 5 * T;
  ull lt = (1ull << lane) - 1ull;
  if (wave == 0) {                 // A: center forward, row (a, j>a), contiguous bits
    unsigned run = baseA[a];
    int len = N_ - 1 - a;
    ll rb = rowstart(a);
    int steps = (len + 63) >> 6;
    for (int k = 0; k < steps; ++k) {
      int idx = (k << 6) + lane;
      bool v = false;
      if (idx < len) { ll b = rb + idx; v = (mask64[b >> 6] >> (b & 63)) & 1ull; }
      ull bal = __ballot(v);
      if (v) {
        ll pos = (ll)(run + (unsigned)__popcll(bal & lt));
        oi[pos] = (float)a; oj[pos] = (float)(a + 1 + idx); ov[pos] = 1.f;
        // offset == 0 already via memset
      }
      run += (unsigned)__popcll(bal);
    }
  } else if (wave == 1) {          // B: shifted forward (s, a, j), offset = -sv[s]
    unsigned run = baseB[a];
    for (int s = 0; s < S; ++s) {
      ll bb = Pc + ((ll)s << 20) + ((ll)a << 10);
      float ox = -ssv[s][0], oy = -ssv[s][1], oz = -ssv[s][2];
      for (int k = 0; k < 16; ++k) {
        int j = (k << 6) + lane;
        ll b = bb + j;
        bool v = (mask64[b >> 6] >> (b & 63)) & 1ull;
        ull bal = __ballot(v);
        if (v) {
          ll pos = (ll)(run + (unsigned)__popcll(bal & lt));
          oi[pos] = (float)a; oj[pos] = (float)j; ov[pos] = 1.f;
          oo[3 * pos + 0] = ox; oo[3 * pos + 1] = oy; oo[3 * pos + 2] = oz;
        }
        run += (unsigned)__popcll(bal);
      }
    }
  } else if (wave == 2) {          // C: center reversed (i < a, a)
    unsigned run = baseC[a];
    int steps = (a + 63) >> 6;
    for (int k = 0; k < steps; ++k) {
      int i = (k << 6) + lane;
      bool v = false;
      if (i < a) { ll b = rowstart(i) + (a - i - 1); v = (mask64[b >> 6] >> (b & 63)) & 1ull; }
      ull bal = __ballot(v);
      if (v) {
        ll pos = (ll)(run + (unsigned)__popcll(bal & lt));
        oi[pos] = (float)a; oj[pos] = (float)i; ov[pos] = 1.f;
      }
      run += (unsigned)__popcll(bal);
    }
  } else {                         // D: shifted reversed (s, i, a), offset = +sv[s]
    unsigned run = baseD[a];
    for (int s = 0; s < S; ++s) {
      ll bb = Pc + ((ll)s << 20) + a;
      float ox = ssv[s][0], oy = ssv[s][1], oz = ssv[s][2];
      for (int k = 0; k < 16; ++k) {
        int i = (k << 6) + lane;
        ll b = bb + ((ll)i << 10);
        bool v = (mask64[b >> 6] >> (b & 63)) & 1ull;
        ull bal = __ballot(v);
        if (v) {
          ll pos = (ll)(run + (unsigned)__popcll(bal & lt));
          oi[pos] = (float)a; oj[pos] = (float)i; ov[pos] = 1.f;
          oo[3 * pos + 0] = ox; oo[3 * pos + 1] = oy; oo[3 * pos + 2] = oz;
        }
        run += (unsigned)__popcll(bal);
      }
    }
  }
}

// ---------------- kernel 4: bulk invalid writer (idx regions only; offsets/valid pre-zeroed)
__global__ __launch_bounds__(BLK) void k_invalid(
    const ull* __restrict__ mask64, const unsigned* __restrict__ blockOff,
    const unsigned* __restrict__ scal, ll Pc, ll P, ll T,
    float* __restrict__ out)
{
  __shared__ unsigned wtot[4];
  int tid = threadIdx.x, lane = tid & 63, wave = tid >> 6;
  ll chunk = (ll)blockIdx.x * CHUNK;
  unsigned Vp = scal[0], V = scal[1];
  unsigned run = blockOff[blockIdx.x];
  ll invDelta = P - (ll)Vp;
  float* oi = out;
  float* oj = out + T;
  ull lt = (1ull << lane) - 1ull;
  for (int r = 0; r < RNDS; ++r) {
    ll p = chunk + (ll)r * BLK + tid;
    bool inr = (p < P);
    bool v = false;
    if (inr) v = (mask64[p >> 6] >> (p & 63)) & 1ull;
    ull bal = __ballot(v);
    if (lane == 0) wtot[wave] = (unsigned)__popcll(bal);
    __syncthreads();
    unsigned wexcl = 0, rtot = 0;
#pragma unroll
    for (int w2 = 0; w2 < 4; ++w2) {
      unsigned c = wtot[w2];
      if (w2 < wave) wexcl += c;
      rtot += c;
    }
    if (inr && !v) {
      unsigned pref = run + wexcl + (unsigned)__popcll(bal & lt);
      ll posF = (ll)V + (p - (ll)pref);   // # invalid before p, after valid region
      ll posR = posF + invDelta;          // mirrored second half
      int i, j;
      if (p < Pc) {
        decode_center(p, i, j);
      } else {
        ll q = p - Pc;
        i = (int)((q >> 10) & (N_ - 1));
        j = (int)(q & (N_ - 1));
      }
      oi[posF] = (float)i; oj[posF] = (float)j;
      oi[posR] = (float)j; oj[posR] = (float)i;
    }
    run += rtot;
    __syncthreads();
  }
}

static inline unsigned char* alignup(unsigned char* p, size_t a) {
  return (unsigned char*)(((uintptr_t)p + a - 1) & ~(uintptr_t)(a - 1));
}

extern "C" void kernel_launch(void* const* d_in, const int* in_sizes, int n_in,
                              void* d_out, int out_size, void* d_ws, size_t ws_size,
                              hipStream_t stream)
{
  const float* pos = (const float*)d_in[0];
  const float* box = (const float*)d_in[1];
  const int* shifts = (const int*)d_in[2];
  int S = in_sizes[2] / 3;                       // 13
  ll Pc = (ll)N_ * (N_ - 1) / 2;                 // 523776
  ll P = Pc + (ll)S * N_ * N_;                   // 14,155,264
  ll T = 2 * P;                                  // 28,310,528
  float* out = (float*)d_out;
  int nb = (int)((P + CHUNK - 1) / CHUNK);       // 864

  unsigned char* w = (unsigned char*)d_ws;
  ull* mask64 = (ull*)w;
  w += ((P + 63) / 64) * sizeof(ull);
  w = alignup(w, 256);
  unsigned* blockCount = (unsigned*)w; w += (size_t)nb * 4;
  w = alignup(w, 256);
  unsigned* blockOff = (unsigned*)w;   w += (size_t)nb * 4;
  w = alignup(w, 256);
  unsigned* cnt = (unsigned*)w;        w += (size_t)4 * N_ * 4;  // A,B,C,D contiguous
  unsigned* cntA = cnt, *cntB = cnt + N_, *cntC = cnt + 2 * N_, *cntD = cnt + 3 * N_;
  unsigned* base = (unsigned*)w;       w += (size_t)4 * N_ * 4;
  unsigned* baseA = base, *baseB = base + N_, *baseC = base + 2 * N_, *baseD = base + 3 * N_;
  unsigned* scal = (unsigned*)w;       w += 64;

  // zero atomic counters; zero offset ([2T,5T)) and valid ([5T,6T)) output regions
  hipMemsetAsync(cnt, 0, (size_t)4 * N_ * sizeof(unsigned), stream);
  hipMemsetAsync(out + 2 * T, 0, (size_t)(4 * T) * sizeof(float), stream);

  k_classify<<<nb, BLK, 0, stream>>>(pos, box, shifts, S, Pc, P,
                                     mask64, blockCount, cntA, cntB, cntC, cntD);
  k_scan<<<1, 1024, 0, stream>>>(blockCount, blockOff, nb,
                                 cntA, cntB, cntC, cntD,
                                 baseA, baseB, baseC, baseD, scal);
  k_valid<<<N_, BLK, 0, stream>>>(mask64, box, shifts, S, Pc, T,
                                  baseA, baseB, baseC, baseD, out);
  k_invalid<<<nb, BLK, 0, stream>>>(mask64, blockOff, scal, Pc, P, T, out);
}